// Round 1
// baseline (286.081 us; speedup 1.0000x reference)
//
#include <hip/hip_runtime.h>
#include <stdint.h>

// TopKMS (OHEM top-k MSE): per-row MSE over [N, 512] fp32, mean of top-30% rows.
// R7: top-5 rocprof showed ALL our kernels < 76 us (fills dominate) -> prior
// "phase A at 2.5 TB/s" was stale. Remaining costs: phase A ~70 us (vs 41 us
// roofline) and a heavy phase B (single-block merge reading 512 KB of partials
// through one CU + 16-block hist + 2 launch gaps).
// Changes: (1) phase A: plain (non-NT) loads, 4 rows/wave/iter = 16 in-flight
// 16B loads/lane, float4 rowmse store; (2) phase B: single global histogram
// built with global atomics (only non-empty bins flushed, ~26K atomics),
// 64 hist blocks, merge reads 32 KB instead of 512 KB; (3) histogram zeroed
// for free by block 0 of phase A (stream-ordered, survives ws re-poison).

#define D_FEAT 512
#define NBINS 4096          // 256 bins/octave over [2^-8, 2^8)
#define HIST_SHIFT 15       // 8 mantissa bits
#define HIST_BASE (119 << 8)
#define MAIN_BLOCKS 2048
#define MAIN_THREADS 256
#define ROWS_PER_WAVE 4
#define HB_BLOCKS 64
#define HB_THREADS 256
#define SEL_THREADS 1024

typedef float f32x4 __attribute__((ext_vector_type(4)));

// ---------------- Phase A: per-row MSE, grid-stride, 4 rows/wave ------------
__global__ __launch_bounds__(MAIN_THREADS) void mse_rows_kernel(
    const float* __restrict__ input,
    const float* __restrict__ target,
    int n_rows,
    float* __restrict__ rowmse,
    int* __restrict__ g_cnt,        // may be null (fallback path)
    float* __restrict__ g_sum)
{
    // Free histogram zeroing: block 0 only; visible to phase B via stream order.
    if (g_cnt != nullptr && blockIdx.x == 0) {
        for (int i = threadIdx.x; i < NBINS; i += MAIN_THREADS) {
            g_cnt[i] = 0;
            g_sum[i] = 0.0f;
        }
    }

    const int lane   = threadIdx.x & 63;
    const int wave   = (blockIdx.x * MAIN_THREADS + threadIdx.x) >> 6;
    const int nwaves = (MAIN_BLOCKS * MAIN_THREADS) >> 6;   // 8192
    const float inv_d = 1.0f / (float)D_FEAT;

    for (int row = wave * ROWS_PER_WAVE; row < n_rows;
         row += ROWS_PER_WAVE * nwaves) {

        float acc[ROWS_PER_WAVE];

        // 16 independent 16B loads issued before any reduction (row bases are
        // wave-uniform -> SGPR bases; per-lane voffset + imm offsets).
        #pragma unroll
        for (int j = 0; j < ROWS_PER_WAVE; ++j) {
            const int r = (row + j < n_rows) ? (row + j) : (n_rows - 1);
            const f32x4* __restrict__ a = (const f32x4*)(input  + (size_t)r * D_FEAT);
            const f32x4* __restrict__ b = (const f32x4*)(target + (size_t)r * D_FEAT);
            f32x4 A0 = a[lane];
            f32x4 A1 = a[lane + 64];
            f32x4 B0 = b[lane];
            f32x4 B1 = b[lane + 64];
            f32x4 d0 = A0 - B0;
            f32x4 d1 = A1 - B1;
            acc[j] = d0.x*d0.x + d0.y*d0.y + d0.z*d0.z + d0.w*d0.w
                   + d1.x*d1.x + d1.y*d1.y + d1.z*d1.z + d1.w*d1.w;
        }

        #pragma unroll
        for (int off = 32; off > 0; off >>= 1) {
            #pragma unroll
            for (int j = 0; j < ROWS_PER_WAVE; ++j)
                acc[j] += __shfl_xor(acc[j], off, 64);
        }

        if (lane == 0) {
            if (row + ROWS_PER_WAVE <= n_rows) {
                f32x4 o = { acc[0] * inv_d, acc[1] * inv_d,
                            acc[2] * inv_d, acc[3] * inv_d };
                *(f32x4*)(rowmse + row) = o;   // row % 4 == 0, 16B aligned
            } else {
                for (int j = 0; j < ROWS_PER_WAVE; ++j)
                    if (row + j < n_rows) rowmse[row + j] = acc[j] * inv_d;
            }
        }
    }
}

// ------- Phase B1: per-block LDS histogram -> global atomic merge -----------
__global__ __launch_bounds__(HB_THREADS) void hist_kernel(
    const float* __restrict__ rowmse,
    int n_rows,
    int* __restrict__ g_cnt,
    float* __restrict__ g_sum)
{
    __shared__ int   cnt[NBINS];
    __shared__ float sum[NBINS];
    const int t = threadIdx.x;

    for (int i = t; i < NBINS; i += HB_THREADS) { cnt[i] = 0; sum[i] = 0.0f; }
    __syncthreads();

    const int chunk = (n_rows + HB_BLOCKS - 1) / HB_BLOCKS;   // 1024
    const int lo = blockIdx.x * chunk;
    const int hi = min(n_rows, lo + chunk);

    for (int i = lo + t; i < hi; i += HB_THREADS) {
        float v = rowmse[i];
        uint32_t bits = __float_as_uint(v);
        int bin = (int)(bits >> HIST_SHIFT) - HIST_BASE;
        bin = bin < 0 ? 0 : (bin > NBINS - 1 ? NBINS - 1 : bin);
        atomicAdd(&cnt[bin], 1);    // ds_add, low contention (~1k rows/block)
        atomicAdd(&sum[bin], v);
    }
    __syncthreads();

    // Flush only non-empty bins: rowmse clusters in ~200 bins, so ~few hundred
    // global atomics per block instead of 8192.
    for (int i = t; i < NBINS; i += HB_THREADS) {
        int c = cnt[i];
        if (c != 0) {
            atomicAdd(&g_cnt[i], c);
            atomicAdd(&g_sum[i], sum[i]);
        }
    }
}

// --------- Phase B2: single-block scan of the 32 KB histogram ---------------
__global__ __launch_bounds__(SEL_THREADS) void scan_select_kernel(
    const int* __restrict__ g_cnt,
    const float* __restrict__ g_sum,
    int k,
    float* __restrict__ out)
{
    __shared__ int   cnt[NBINS];
    __shared__ float sum[NBINS];
    __shared__ int   cs[SEL_THREADS];
    __shared__ float ss[SEL_THREADS];
    const int t = threadIdx.x;

    for (int i = t; i < NBINS; i += SEL_THREADS) {
        cnt[i] = g_cnt[i];
        sum[i] = g_sum[i];
    }
    __syncthreads();

    // descending chunks: thread t owns bins [start - ch + 1, start]
    const int ch = NBINS / SEL_THREADS;   // 4
    const int start = NBINS - 1 - t * ch;

    int   c_t = 0;
    float s_t = 0.0f;
    #pragma unroll
    for (int j = 0; j < ch; ++j) { c_t += cnt[start - j]; s_t += sum[start - j]; }
    cs[t] = c_t;
    ss[t] = s_t;
    __syncthreads();

    // Hillis-Steele inclusive scan (top -> bottom order)
    for (int off = 1; off < SEL_THREADS; off <<= 1) {
        int cv = 0; float sv = 0.0f;
        if (t >= off) { cv = cs[t - off]; sv = ss[t - off]; }
        __syncthreads();
        cs[t] += cv;
        ss[t] += sv;
        __syncthreads();
    }

    const int   c_incl   = cs[t];
    const int   c_before = c_incl - c_t;
    const float s_before = ss[t] - s_t;

    if (c_before < k && k <= c_incl) {
        int   cum = c_before;
        float s   = s_before;
        float result = 0.0f;
        for (int j = 0; j < ch; ++j) {
            int b = start - j;
            int c = cnt[b];
            if (c == 0) continue;
            if (cum + c >= k) {
                int need = k - cum;
                float avg = sum[b] / (float)c;   // bin mean, tighter than center
                result = (s + (float)need * avg) / (float)k;
                break;
            }
            cum += c;
            s   += sum[b];
        }
        out[0] = result;
    }
}

// ---- Fallback single-block select (only used if d_ws is tiny) ---------------
__global__ __launch_bounds__(SEL_THREADS) void select_topk_kernel(
    const float* __restrict__ rowmse,
    int n_rows, int k,
    float* __restrict__ out)
{
    __shared__ int   cnt[NBINS];
    __shared__ float sum[NBINS];
    __shared__ int   cs[SEL_THREADS];
    __shared__ float ss[SEL_THREADS];
    const int t = threadIdx.x;

    for (int i = t; i < NBINS; i += SEL_THREADS) { cnt[i] = 0; sum[i] = 0.0f; }
    __syncthreads();
    for (int i = t; i < n_rows; i += SEL_THREADS) {
        float v = rowmse[i];
        uint32_t bits = __float_as_uint(v);
        int bin = (int)(bits >> HIST_SHIFT) - HIST_BASE;
        bin = bin < 0 ? 0 : (bin > NBINS - 1 ? NBINS - 1 : bin);
        atomicAdd(&cnt[bin], 1);
        atomicAdd(&sum[bin], v);
    }
    __syncthreads();

    const int ch = NBINS / SEL_THREADS;
    const int start = NBINS - 1 - t * ch;
    int c_t = 0; float s_t = 0.0f;
    #pragma unroll
    for (int j = 0; j < ch; ++j) { c_t += cnt[start - j]; s_t += sum[start - j]; }
    cs[t] = c_t; ss[t] = s_t;
    __syncthreads();
    for (int off = 1; off < SEL_THREADS; off <<= 1) {
        int cv = 0; float sv = 0.0f;
        if (t >= off) { cv = cs[t - off]; sv = ss[t - off]; }
        __syncthreads();
        cs[t] += cv; ss[t] += sv;
        __syncthreads();
    }
    const int c_incl = cs[t], c_before = c_incl - c_t;
    const float s_before = ss[t] - s_t;
    if (c_before < k && k <= c_incl) {
        int cum = c_before; float s = s_before; float result = 0.0f;
        for (int j = 0; j < ch; ++j) {
            int b = start - j;
            int c = cnt[b];
            if (c == 0) continue;
            if (cum + c >= k) {
                int need = k - cum;
                result = (s + (float)need * (sum[b] / (float)c)) / (float)k;
                break;
            }
            cum += c; s += sum[b];
        }
        out[0] = result;
    }
}

extern "C" void kernel_launch(void* const* d_in, const int* in_sizes, int n_in,
                              void* d_out, int out_size, void* d_ws, size_t ws_size,
                              hipStream_t stream)
{
    const float* input  = (const float*)d_in[0];
    const float* target = (const float*)d_in[1];
    float* out = (float*)d_out;

    const int total  = in_sizes[0];
    const int n_rows = total / D_FEAT;            // 65536
    int k = (int)(0.3 * (double)n_rows);          // matches int(K_FRAC * n)
    if (k < 1) k = 1;
    if (k > n_rows) k = n_rows;

    const size_t rowmse_bytes = (size_t)n_rows * sizeof(float);
    const size_t hist_bytes   = (size_t)NBINS * (sizeof(int) + sizeof(float));
    const bool   big_ws       = (ws_size >= rowmse_bytes + hist_bytes);

    float* rowmse = (float*)d_ws;
    int*   g_cnt  = big_ws ? (int*)((char*)d_ws + rowmse_bytes) : nullptr;
    float* g_sum  = big_ws ? (float*)((char*)d_ws + rowmse_bytes
                                      + (size_t)NBINS * sizeof(int)) : nullptr;

    mse_rows_kernel<<<MAIN_BLOCKS, MAIN_THREADS, 0, stream>>>(
        input, target, n_rows, rowmse, g_cnt, g_sum);

    if (big_ws) {
        hist_kernel<<<HB_BLOCKS, HB_THREADS, 0, stream>>>(rowmse, n_rows, g_cnt, g_sum);
        scan_select_kernel<<<1, SEL_THREADS, 0, stream>>>(g_cnt, g_sum, k, out);
    } else {
        select_topk_kernel<<<1, SEL_THREADS, 0, stream>>>(rowmse, n_rows, k, out);
    }
}

// Round 2
// 277.593 us; speedup vs baseline: 1.0306x; 1.0306x over previous
//
#include <hip/hip_runtime.h>
#include <stdint.h>

// TopKMS (OHEM top-k MSE): per-row MSE over [N, 512] fp32, mean of top-30% rows.
// R8: R7's 4-rows/wave regressed phase A to 101 us because the compiler capped
// VGPR_Count at 40 -- 16 in-flight f32x4 loads need 64 VGPRs, so it batched
// them with interleaved waitcnts (MLP destroyed; 2.65 TB/s effective, VALUBusy
// 2.7%). Also FETCH=134MB = exactly half the input: the poison fill streams
// (no-allocate), so half the input survives in L3 across replays -- plain
// loads keep that benefit.
// Fix: one-shot grid (8192 blocks x 256 thr), 2 rows/wave, 8 straight-line
// f32x4 loads, no loop -> no register-pressure batching; MLP via TLP (32768
// waves). Phase B unchanged from R7 (global-atomic hist + 32KB scan -- that
// part got cheaper last round).

#define D_FEAT 512
#define NBINS 4096          // 256 bins/octave over [2^-8, 2^8)
#define HIST_SHIFT 15       // 8 mantissa bits
#define HIST_BASE (119 << 8)
#define A_THREADS 256
#define ROWS_PER_WAVE 2
#define HB_BLOCKS 64
#define HB_THREADS 256
#define SEL_THREADS 1024

typedef float f32x4 __attribute__((ext_vector_type(4)));
typedef float f32x2 __attribute__((ext_vector_type(2)));

// -------- Phase A: per-row MSE, one-shot, 2 rows/wave, straight-line --------
__global__ __launch_bounds__(A_THREADS) void mse_rows_kernel(
    const float* __restrict__ input,
    const float* __restrict__ target,
    int n_rows,
    float* __restrict__ rowmse,
    int* __restrict__ g_cnt,        // may be null (fallback path)
    float* __restrict__ g_sum)
{
    // Free histogram zeroing: block 0 only; visible to phase B via stream order.
    if (g_cnt != nullptr && blockIdx.x == 0) {
        for (int i = threadIdx.x; i < NBINS; i += A_THREADS) {
            g_cnt[i] = 0;
            g_sum[i] = 0.0f;
        }
    }

    const int lane = threadIdx.x & 63;
    const int wave = (blockIdx.x * A_THREADS + threadIdx.x) >> 6;
    const int row  = wave * ROWS_PER_WAVE;
    if (row >= n_rows) return;

    const int  row1 = row + 1;
    const bool has1 = (row1 < n_rows);
    const int  r1   = has1 ? row1 : row;
    const float inv_d = 1.0f / (float)D_FEAT;

    const f32x4* __restrict__ a0 = (const f32x4*)(input  + (size_t)row * D_FEAT);
    const f32x4* __restrict__ b0 = (const f32x4*)(target + (size_t)row * D_FEAT);
    const f32x4* __restrict__ a1 = (const f32x4*)(input  + (size_t)r1  * D_FEAT);
    const f32x4* __restrict__ b1 = (const f32x4*)(target + (size_t)r1  * D_FEAT);

    // 8 independent 16B loads, all issued before any dependent math.
    f32x4 A00 = a0[lane];
    f32x4 A01 = a0[lane + 64];
    f32x4 B00 = b0[lane];
    f32x4 B01 = b0[lane + 64];
    f32x4 A10 = a1[lane];
    f32x4 A11 = a1[lane + 64];
    f32x4 B10 = b1[lane];
    f32x4 B11 = b1[lane + 64];

    f32x4 d0 = A00 - B00;
    f32x4 d1 = A01 - B01;
    f32x4 d2 = A10 - B10;
    f32x4 d3 = A11 - B11;

    float acc0 = d0.x*d0.x + d0.y*d0.y + d0.z*d0.z + d0.w*d0.w
               + d1.x*d1.x + d1.y*d1.y + d1.z*d1.z + d1.w*d1.w;
    float acc1 = d2.x*d2.x + d2.y*d2.y + d2.z*d2.z + d2.w*d2.w
               + d3.x*d3.x + d3.y*d3.y + d3.z*d3.z + d3.w*d3.w;

    #pragma unroll
    for (int off = 32; off > 0; off >>= 1) {
        acc0 += __shfl_xor(acc0, off, 64);
        acc1 += __shfl_xor(acc1, off, 64);
    }

    if (lane == 0) {
        if (has1) {
            f32x2 o = { acc0 * inv_d, acc1 * inv_d };
            *(f32x2*)(rowmse + row) = o;     // row % 2 == 0, 8B aligned
        } else {
            rowmse[row] = acc0 * inv_d;
        }
    }
}

// ------- Phase B1: per-block LDS histogram -> global atomic merge -----------
__global__ __launch_bounds__(HB_THREADS) void hist_kernel(
    const float* __restrict__ rowmse,
    int n_rows,
    int* __restrict__ g_cnt,
    float* __restrict__ g_sum)
{
    __shared__ int   cnt[NBINS];
    __shared__ float sum[NBINS];
    const int t = threadIdx.x;

    for (int i = t; i < NBINS; i += HB_THREADS) { cnt[i] = 0; sum[i] = 0.0f; }
    __syncthreads();

    const int chunk = (n_rows + HB_BLOCKS - 1) / HB_BLOCKS;   // 1024
    const int lo = blockIdx.x * chunk;
    const int hi = min(n_rows, lo + chunk);

    for (int i = lo + t; i < hi; i += HB_THREADS) {
        float v = rowmse[i];
        uint32_t bits = __float_as_uint(v);
        int bin = (int)(bits >> HIST_SHIFT) - HIST_BASE;
        bin = bin < 0 ? 0 : (bin > NBINS - 1 ? NBINS - 1 : bin);
        atomicAdd(&cnt[bin], 1);    // ds_add, low contention (~1k rows/block)
        atomicAdd(&sum[bin], v);
    }
    __syncthreads();

    // Flush only non-empty bins: rowmse clusters in a few hundred bins.
    for (int i = t; i < NBINS; i += HB_THREADS) {
        int c = cnt[i];
        if (c != 0) {
            atomicAdd(&g_cnt[i], c);
            atomicAdd(&g_sum[i], sum[i]);
        }
    }
}

// --------- Phase B2: single-block scan of the 32 KB histogram ---------------
__global__ __launch_bounds__(SEL_THREADS) void scan_select_kernel(
    const int* __restrict__ g_cnt,
    const float* __restrict__ g_sum,
    int k,
    float* __restrict__ out)
{
    __shared__ int   cnt[NBINS];
    __shared__ float sum[NBINS];
    __shared__ int   cs[SEL_THREADS];
    __shared__ float ss[SEL_THREADS];
    const int t = threadIdx.x;

    for (int i = t; i < NBINS; i += SEL_THREADS) {
        cnt[i] = g_cnt[i];
        sum[i] = g_sum[i];
    }
    __syncthreads();

    // descending chunks: thread t owns bins [start - ch + 1, start]
    const int ch = NBINS / SEL_THREADS;   // 4
    const int start = NBINS - 1 - t * ch;

    int   c_t = 0;
    float s_t = 0.0f;
    #pragma unroll
    for (int j = 0; j < ch; ++j) { c_t += cnt[start - j]; s_t += sum[start - j]; }
    cs[t] = c_t;
    ss[t] = s_t;
    __syncthreads();

    // Hillis-Steele inclusive scan (top -> bottom order)
    for (int off = 1; off < SEL_THREADS; off <<= 1) {
        int cv = 0; float sv = 0.0f;
        if (t >= off) { cv = cs[t - off]; sv = ss[t - off]; }
        __syncthreads();
        cs[t] += cv;
        ss[t] += sv;
        __syncthreads();
    }

    const int   c_incl   = cs[t];
    const int   c_before = c_incl - c_t;
    const float s_before = ss[t] - s_t;

    if (c_before < k && k <= c_incl) {
        int   cum = c_before;
        float s   = s_before;
        float result = 0.0f;
        for (int j = 0; j < ch; ++j) {
            int b = start - j;
            int c = cnt[b];
            if (c == 0) continue;
            if (cum + c >= k) {
                int need = k - cum;
                float avg = sum[b] / (float)c;   // bin mean, tighter than center
                result = (s + (float)need * avg) / (float)k;
                break;
            }
            cum += c;
            s   += sum[b];
        }
        out[0] = result;
    }
}

// ---- Fallback single-block select (only used if d_ws is tiny) ---------------
__global__ __launch_bounds__(SEL_THREADS) void select_topk_kernel(
    const float* __restrict__ rowmse,
    int n_rows, int k,
    float* __restrict__ out)
{
    __shared__ int   cnt[NBINS];
    __shared__ float sum[NBINS];
    __shared__ int   cs[SEL_THREADS];
    __shared__ float ss[SEL_THREADS];
    const int t = threadIdx.x;

    for (int i = t; i < NBINS; i += SEL_THREADS) { cnt[i] = 0; sum[i] = 0.0f; }
    __syncthreads();
    for (int i = t; i < n_rows; i += SEL_THREADS) {
        float v = rowmse[i];
        uint32_t bits = __float_as_uint(v);
        int bin = (int)(bits >> HIST_SHIFT) - HIST_BASE;
        bin = bin < 0 ? 0 : (bin > NBINS - 1 ? NBINS - 1 : bin);
        atomicAdd(&cnt[bin], 1);
        atomicAdd(&sum[bin], v);
    }
    __syncthreads();

    const int ch = NBINS / SEL_THREADS;
    const int start = NBINS - 1 - t * ch;
    int c_t = 0; float s_t = 0.0f;
    #pragma unroll
    for (int j = 0; j < ch; ++j) { c_t += cnt[start - j]; s_t += sum[start - j]; }
    cs[t] = c_t; ss[t] = s_t;
    __syncthreads();
    for (int off = 1; off < SEL_THREADS; off <<= 1) {
        int cv = 0; float sv = 0.0f;
        if (t >= off) { cv = cs[t - off]; sv = ss[t - off]; }
        __syncthreads();
        cs[t] += cv; ss[t] += sv;
        __syncthreads();
    }
    const int c_incl = cs[t], c_before = c_incl - c_t;
    const float s_before = ss[t] - s_t;
    if (c_before < k && k <= c_incl) {
        int cum = c_before; float s = s_before; float result = 0.0f;
        for (int j = 0; j < ch; ++j) {
            int b = start - j;
            int c = cnt[b];
            if (c == 0) continue;
            if (cum + c >= k) {
                int need = k - cum;
                result = (s + (float)need * (sum[b] / (float)c)) / (float)k;
                break;
            }
            cum += c; s += sum[b];
        }
        out[0] = result;
    }
}

extern "C" void kernel_launch(void* const* d_in, const int* in_sizes, int n_in,
                              void* d_out, int out_size, void* d_ws, size_t ws_size,
                              hipStream_t stream)
{
    const float* input  = (const float*)d_in[0];
    const float* target = (const float*)d_in[1];
    float* out = (float*)d_out;

    const int total  = in_sizes[0];
    const int n_rows = total / D_FEAT;            // 65536
    int k = (int)(0.3 * (double)n_rows);          // matches int(K_FRAC * n)
    if (k < 1) k = 1;
    if (k > n_rows) k = n_rows;

    const size_t rowmse_bytes = (size_t)n_rows * sizeof(float);
    const size_t hist_bytes   = (size_t)NBINS * (sizeof(int) + sizeof(float));
    const bool   big_ws       = (ws_size >= rowmse_bytes + hist_bytes);

    float* rowmse = (float*)d_ws;
    int*   g_cnt  = big_ws ? (int*)((char*)d_ws + rowmse_bytes) : nullptr;
    float* g_sum  = big_ws ? (float*)((char*)d_ws + rowmse_bytes
                                      + (size_t)NBINS * sizeof(int)) : nullptr;

    // One-shot grid: each wave handles exactly ROWS_PER_WAVE rows.
    const int rows_per_block = (A_THREADS / 64) * ROWS_PER_WAVE;   // 8
    const int a_blocks = (n_rows + rows_per_block - 1) / rows_per_block;  // 8192

    mse_rows_kernel<<<a_blocks, A_THREADS, 0, stream>>>(
        input, target, n_rows, rowmse, g_cnt, g_sum);

    if (big_ws) {
        hist_kernel<<<HB_BLOCKS, HB_THREADS, 0, stream>>>(rowmse, n_rows, g_cnt, g_sum);
        scan_select_kernel<<<1, SEL_THREADS, 0, stream>>>(g_cnt, g_sum, k, out);
    } else {
        select_topk_kernel<<<1, SEL_THREADS, 0, stream>>>(rowmse, n_rows, k, out);
    }
}